// Round 12
// baseline (267.612 us; speedup 1.0000x reference)
//
#include <hip/hip_runtime.h>
#include <hip/hip_bf16.h>
#include <stdint.h>

#define N_NODES 100000
#define N_EDGES 1600000
#define CH 128
#define N_REL 8
#define N_PAD 100096            // N_NODES rounded up to multiple of 128
#define N_KEYS (N_NODES * N_REL)

#define NBKT 782                // N_PAD / 128 buckets (= fused grid)
#define CHUNK_E 1024            // edges per chunk (R12: halved -> 2x blocks,
                                // half the per-block serial depth; prep was
                                // latency-bound per block, not BW-bound)
#define NCHUNK 1563             // ceil(N_EDGES / CHUNK_E)
#define OFFS_STRIDE 784         // per-chunk offset row (782 buckets + total + pad)
#define PERM_LDS_CAP 4096       // per-bucket edges ~2046 +- 45 -> 45-sigma margin

using frag_ab = __attribute__((ext_vector_type(8))) short;  // 8 bf16
using frag_cd = __attribute__((ext_vector_type(4))) float;  // 4 fp32

__device__ __forceinline__ short f2bs(float f) {
    union { __hip_bfloat16 h; short s; } u;
    u.h = __float2bfloat16(f);
    return u.s;
}

__device__ __forceinline__ uint32_t pack2bf(float a, float b) {
    union { __hip_bfloat16 h; unsigned short s; } ua, ub;
    ua.h = __float2bfloat16(a); ub.h = __float2bfloat16(b);
    return (uint32_t)ua.s | ((uint32_t)ub.s << 16);
}

__device__ __forceinline__ float bf_lo(uint32_t u) { return __uint_as_float(u << 16); }
__device__ __forceinline__ float bf_hi(uint32_t u) { return __uint_as_float(u & 0xffff0000u); }

// ======================= prep: compact per-chunk CSR (+xconv +bconv) =======================
// 1563 blocks, 1024 edges each. Pass 1 packs entries to LDS + counts; 256-wide
// scan -> exclusive offsets (offs[c][784]); pass 2 compacts in LDS; linear 4KB
// uint4 writeout. Entry: src<<10 | (dst&127)<<3 | rel. Zero global atomics.

__global__ __launch_bounds__(256)
void prep_kernel(const int* __restrict__ ei, const int* __restrict__ et,
                 uint32_t* __restrict__ ents, int* __restrict__ offs,
                 const float* __restrict__ x, short* __restrict__ xb,
                 const float* __restrict__ root, const float* __restrict__ W,
                 short* __restrict__ Bsw) {
    __shared__ uint32_t esave[CHUNK_E];   // 4 KB: packed entries, arrival order
    __shared__ uint32_t csave[CHUNK_E];   // 4 KB: compact (bucket-sorted) entries
    __shared__ short bsave[CHUNK_E];      // 2 KB: bucket id per entry (-1 invalid)
    __shared__ int cnt[NBKT];             // count -> cursor
    __shared__ int scan_t[256];
    const int tid = threadIdx.x;
    const int c = blockIdx.x;
    const int g = blockIdx.x * 256 + tid;

    // --- bconv rides on blocks 0..71 ---
    if (g < 9 * 2048) {
        int chunk = g >> 11, entry = g & 2047;
        int m16 = entry & 15, ct = (entry >> 4) & 7, quad = (entry >> 7) & 3, ks = entry >> 9;
        const float* src = (chunk == 0) ? root : W + (size_t)(chunk - 1) * CH * CH;
        int col = ct * 16 + m16, kb = ks * 32 + quad * 8;
        frag_ab f;
#pragma unroll
        for (int j = 0; j < 8; ++j) f[j] = f2bs(src[(size_t)(kb + j) * CH + col]);
        *(frag_ab*)(Bsw + (size_t)g * 8) = f;
    }

    // --- xconv grid-stride: x fp32 -> bf16 (4 iters/thread over 1563x256 grid) ---
    {
        const int nst = NCHUNK * 256;
        const float4* xp = (const float4*)x;
        for (int gi = g; gi < N_NODES * CH / 8; gi += nst) {
            float4 a = xp[(size_t)gi * 2], bb = xp[(size_t)gi * 2 + 1];
            frag_ab f;
            f[0] = f2bs(a.x); f[1] = f2bs(a.y); f[2] = f2bs(a.z); f[3] = f2bs(a.w);
            f[4] = f2bs(bb.x); f[5] = f2bs(bb.y); f[6] = f2bs(bb.z); f[7] = f2bs(bb.w);
            *(frag_ab*)(xb + (size_t)gi * 8) = f;
        }
    }

    for (int i = tid; i < NBKT; i += 256) cnt[i] = 0;
    __syncthreads();
    // --- pass 1: read edges (coalesced), pack to LDS, count per bucket ---
#pragma unroll
    for (int j = 0; j < 4; ++j) {
        const int li = j * 256 + tid;
        const int e = c * CHUNK_E + li;
        if (e < N_EDGES) {
            const int dst = ei[N_EDGES + e];
            const int src = ei[e];
            const int r = et[e];
            const int b = dst >> 7;
            atomicAdd(&cnt[b], 1);
            esave[li] = ((uint32_t)src << 10) | ((uint32_t)(dst & 127) << 3) | (uint32_t)r;
            bsave[li] = (short)b;
        } else {
            bsave[li] = -1;
        }
    }
    __syncthreads();
    // --- scan cnt[0..781] -> exclusive offsets (thread t owns 4t..4t+3) ---
    const int b4 = 4 * tid;
    int c0 = (b4 < NBKT) ? cnt[b4] : 0;
    int c1 = (b4 + 1 < NBKT) ? cnt[b4 + 1] : 0;
    int c2 = (b4 + 2 < NBKT) ? cnt[b4 + 2] : 0;
    int c3 = (b4 + 3 < NBKT) ? cnt[b4 + 3] : 0;
    const int s4 = c0 + c1 + c2 + c3;
    scan_t[tid] = s4;
    __syncthreads();
    for (int st = 1; st < 256; st <<= 1) {    // Hillis-Steele inclusive
        int u = (tid >= st) ? scan_t[tid - st] : 0;
        __syncthreads();
        scan_t[tid] += u;
        __syncthreads();
    }
    const int excl = scan_t[tid] - s4;
    const int total = scan_t[255];
    {
        const int o0 = excl, o1 = o0 + c0, o2 = o1 + c1, o3 = o2 + c2;
        int* og = offs + (size_t)c * OFFS_STRIDE;
        if (b4 < NBKT)     { cnt[b4]     = o0; og[b4]     = o0; }
        if (b4 + 1 < NBKT) { cnt[b4 + 1] = o1; og[b4 + 1] = o1; }
        if (b4 + 2 < NBKT) { cnt[b4 + 2] = o2; og[b4 + 2] = o2; }
        if (b4 + 3 < NBKT) { cnt[b4 + 3] = o3; og[b4 + 3] = o3; }
        if (tid == 0) og[NBKT] = total;
    }
    __syncthreads();
    // --- pass 2: place entries at compact positions ---
#pragma unroll
    for (int j = 0; j < 4; ++j) {
        const int li = j * 256 + tid;
        const int b = bsave[li];
        if (b >= 0) {
            const int pos = atomicAdd(&cnt[b], 1);
            csave[pos] = esave[li];
        }
    }
    __syncthreads();
    // --- linear writeout: 4 KB as uint4 (1 iter/thread) ---
    {
        const uint4* cs = (const uint4*)csave;
        uint4* dg = (uint4*)(ents + (size_t)c * CHUNK_E);
        dg[tid] = cs[tid];
    }
}

// ======================= FUSED: slice-copy + bin + aggregate + GEMM =======================
// Block b: slice bounds from offs (packed soff<<11|slen), quad-scan (4 chunks/
// thread, 2048 >= 1563) -> stage bases, dense slice copy into stage[] with the
// histogram MERGED into the copy, scan -> cursor/lends, scatter -> perm_lds.
// Root MFMA after scatter. Relation loop unchanged (131-151us structure).
#define ACC_U4(U, B)                                            \
    do {                                                        \
        a[(B)+0] += bf_lo((U).x); a[(B)+1] += bf_hi((U).x);     \
        a[(B)+2] += bf_lo((U).y); a[(B)+3] += bf_hi((U).y);     \
        a[(B)+4] += bf_lo((U).z); a[(B)+5] += bf_hi((U).z);     \
        a[(B)+6] += bf_lo((U).w); a[(B)+7] += bf_hi((U).w);     \
    } while (0)

__global__ __launch_bounds__(512, 4)
void rgcn_fused(const uint32_t* __restrict__ ents, const int* __restrict__ offs,
                const short* __restrict__ xb, const short* __restrict__ Bsw,
                const float* __restrict__ bias, float* __restrict__ out) {
    __shared__ short Ash[128 * 128];        // 32 KB A-tile; aliased in binning
    __shared__ int perm_lds[PERM_LDS_CAP];  // 16 KB
    __shared__ int lends[1025];             // local ends; lends[0] = 0
    __shared__ int spack[NCHUNK];           // 6.1 KB: soff<<11 | slen
    __shared__ int sbase[NCHUNK];           // 6.1 KB: stage base per chunk
    uint32_t* stage  = (uint32_t*)Ash;      // [4096] 16 KB  (alias)
    int*      hist   = (int*)Ash + 4096;    // [1024]  4 KB  (alias)
    int*      cursor = (int*)Ash + 5120;    // [1024]  4 KB  (alias)
    int*      shl    = (int*)Ash + 6144;    // [512]   2 KB  (alias)

    const int tid = threadIdx.x;
    const int wave = tid >> 6, lane = tid & 63;
    const int m16 = lane & 15, quad = lane >> 4;
    const int wm = wave >> 2, wn = wave & 3;     // wave tile: 64 rows x 32 cols
    const int b = blockIdx.x;
    const long B0 = (long)b * 128;

    // ---- P0: slice bounds (offs lines shared by 16 sibling buckets) ----
    for (int c = tid; c < NCHUNK; c += 512) {
        const int s = offs[(size_t)c * OFFS_STRIDE + b];
        const int e = offs[(size_t)c * OFFS_STRIDE + b + 1];
        spack[c] = (s << 11) | (e - s);
    }
    hist[tid] = 0; hist[tid + 512] = 0;
    if (tid == 0) perm_lds[0] = 0;          // safe gather target for empty segs
    __syncthreads();
    // ---- P1: quad-scan slice lengths -> per-chunk stage base ----
    int n_tot;
    {
        const int t4 = 4 * tid;
        int l0 = (t4 < NCHUNK) ? (spack[t4] & 2047) : 0;
        int l1 = (t4 + 1 < NCHUNK) ? (spack[t4 + 1] & 2047) : 0;
        int l2 = (t4 + 2 < NCHUNK) ? (spack[t4 + 2] & 2047) : 0;
        int l3 = (t4 + 3 < NCHUNK) ? (spack[t4 + 3] & 2047) : 0;
        const int ls = l0 + l1 + l2 + l3;
        shl[tid] = ls;
        __syncthreads();
        for (int st = 1; st < 512; st <<= 1) {
            int u = (tid >= st) ? shl[tid - st] : 0;
            __syncthreads();
            shl[tid] += u;
            __syncthreads();
        }
        const int lexcl = shl[tid] - ls;
        if (t4 < NCHUNK)     sbase[t4]     = lexcl;
        if (t4 + 1 < NCHUNK) sbase[t4 + 1] = lexcl + l0;
        if (t4 + 2 < NCHUNK) sbase[t4 + 2] = lexcl + l0 + l1;
        if (t4 + 3 < NCHUNK) sbase[t4 + 3] = lexcl + l0 + l1 + l2;
        __syncthreads();
        n_tot = shl[511];
        if (n_tot > PERM_LDS_CAP) n_tot = PERM_LDS_CAP;
    }
    // ---- P2: dense slice copy into stage + merged histogram ----
#pragma unroll
    for (int k = 0; k < 4; ++k) {
        const int c = 4 * tid + k;
        if (c < NCHUNK) {
            const int sp = spack[c];
            const int s = sp >> 11, nc = sp & 2047, base = sbase[c];
            const uint32_t* srcp = ents + (size_t)c * CHUNK_E + s;
            for (int i = 0; i < nc; ++i) {
                const int pos = base + i;
                const uint32_t v = srcp[i];
                if (pos < PERM_LDS_CAP) {
                    stage[pos] = v;
                    atomicAdd(&hist[v & 1023], 1);
                }
            }
        }
    }
    __syncthreads();
    // ---- P3: scan hist -> cursor + local segment ends ----
    {
        const int h0 = hist[2 * tid], h1 = hist[2 * tid + 1];
        const int s2 = h0 + h1;
        shl[tid] = s2;
        __syncthreads();
        for (int st = 1; st < 512; st <<= 1) {
            int u = (tid >= st) ? shl[tid - st] : 0;
            __syncthreads();
            shl[tid] += u;
            __syncthreads();
        }
        const int excl = shl[tid] - s2;
        cursor[2 * tid]     = excl;
        cursor[2 * tid + 1] = excl + h0;
        if (tid == 0) lends[0] = 0;
        int e1 = excl + h0, e2 = excl + h0 + h1;
        lends[1 + 2 * tid] = (e1 > PERM_LDS_CAP) ? PERM_LDS_CAP : e1;
        lends[2 + 2 * tid] = (e2 > PERM_LDS_CAP) ? PERM_LDS_CAP : e2;
    }
    __syncthreads();
    // ---- P4: scatter stage -> perm_lds (src ids, key-sorted) ----
    for (int i = tid; i < n_tot; i += 512) {
        const uint32_t v = stage[i];
        const int pos = atomicAdd(&cursor[v & 1023], 1);
        if (pos < PERM_LDS_CAP) perm_lds[pos] = (int)(v >> 10);
    }

    // ---- chunk 0 (root): A direct from global xb; overlaps the scatter tail ----
    float bcol[2];
#pragma unroll
    for (int ct = 0; ct < 2; ++ct) bcol[ct] = bias[wn * 32 + ct * 16 + m16];

    frag_cd acc[4][2];
#pragma unroll
    for (int mt = 0; mt < 4; ++mt)
#pragma unroll
        for (int ct = 0; ct < 2; ++ct) acc[mt][ct] = (frag_cd){0.f, 0.f, 0.f, 0.f};

#pragma unroll
    for (int ks = 0; ks < 4; ++ks) {
        frag_ab af[4];
#pragma unroll
        for (int mt = 0; mt < 4; ++mt)
            af[mt] = *(const frag_ab*)(xb + (B0 + wm * 64 + mt * 16 + m16) * CH + ks * 32 + quad * 8);
#pragma unroll
        for (int ct = 0; ct < 2; ++ct) {
            frag_ab bf = *(const frag_ab*)(Bsw + (size_t)((((ks * 4 + quad) * 8) + wn * 2 + ct) * 16 + m16) * 8);
#pragma unroll
            for (int mt = 0; mt < 4; ++mt)
                acc[mt][ct] = __builtin_amdgcn_mfma_f32_16x16x32_bf16(af[mt], bf, acc[mt][ct], 0, 0, 0);
        }
    }
    __syncthreads();   // binning aliases dead, perm_lds/lends ready, Ash free

    // ---- relation loop ----
    const int lrow = tid >> 2;                     // 4-lane group -> one dst row
    const int q4 = tid & 3;
    const uint32_t ch64 = (uint32_t)q4 << 6;       // this lane's 64B channel slice
    const char* xbp = (const char*)xb;
    char* drow = (char*)Ash + lrow * 256;
    const int swz = lrow & 7;

    for (int r = 0; r < N_REL; ++r) {
        const int keyL = lrow * 8 + r;
        const int s = lends[keyL];
        const int e = lends[keyL + 1];
        float a[32];
#pragma unroll
        for (int i = 0; i < 32; ++i) a[i] = 0.f;
        int p0 = perm_lds[(s < e) ? s : 0];
        int p1 = perm_lds[(s + 1 < e) ? s + 1 : ((s < e) ? s : 0)];
        for (int k = s; k < e; k += 2) {
            const char* c0 = xbp + (((size_t)(uint32_t)p0 << 8) | ch64);
            const char* c1 = xbp + (((size_t)(uint32_t)p1 << 8) | ch64);
            const uint4 u0 = *(const uint4*)(c0);
            const uint4 u1 = *(const uint4*)(c0 + 16);
            const uint4 u2 = *(const uint4*)(c0 + 32);
            const uint4 u3 = *(const uint4*)(c0 + 48);
            const uint4 u4 = *(const uint4*)(c1);
            const uint4 u5 = *(const uint4*)(c1 + 16);
            const uint4 u6 = *(const uint4*)(c1 + 32);
            const uint4 u7 = *(const uint4*)(c1 + 48);
            const bool two = (k + 1 < e);
            const int kn = k + 2;
            p0 = perm_lds[(kn < e) ? kn : 0];
            p1 = perm_lds[(kn + 1 < e) ? kn + 1 : 0];
            ACC_U4(u0, 0); ACC_U4(u1, 8); ACC_U4(u2, 16); ACC_U4(u3, 24);
            if (two) { ACC_U4(u4, 0); ACC_U4(u5, 8); ACC_U4(u6, 16); ACC_U4(u7, 24); }
        }
        const int c = e - s;
        const float sc = (c > 1) ? (1.0f / (float)c) : 1.0f;
#pragma unroll
        for (int t = 0; t < 4; ++t) {
            uint4 w;
            w.x = pack2bf(a[t * 8 + 0] * sc, a[t * 8 + 1] * sc);
            w.y = pack2bf(a[t * 8 + 2] * sc, a[t * 8 + 3] * sc);
            w.z = pack2bf(a[t * 8 + 4] * sc, a[t * 8 + 5] * sc);
            w.w = pack2bf(a[t * 8 + 6] * sc, a[t * 8 + 7] * sc);
            *(uint4*)(drow + (((q4 * 4 + t) ^ swz) << 4)) = w;   // swizzled A-tile write
        }
        __syncthreads();
        // ---- MFMA chunk r+1: A from LDS (swizzled ds_read_b128), B from L2-hot Bsw ----
        const short* Bc = Bsw + (size_t)(r + 1) * 2048 * 8;
#pragma unroll
        for (int ks = 0; ks < 4; ++ks) {
            frag_ab af[4];
#pragma unroll
            for (int mt = 0; mt < 4; ++mt) {
                const int lr = wm * 64 + mt * 16 + m16;
                af[mt] = *(const frag_ab*)((const char*)Ash + lr * 256 + (((ks * 4 + quad) ^ (lr & 7)) << 4));
            }
#pragma unroll
            for (int ct = 0; ct < 2; ++ct) {
                frag_ab bf = *(const frag_ab*)(Bc + (size_t)((((ks * 4 + quad) * 8) + wn * 2 + ct) * 16 + m16) * 8);
#pragma unroll
                for (int mt = 0; mt < 4; ++mt)
                    acc[mt][ct] = __builtin_amdgcn_mfma_f32_16x16x32_bf16(af[mt], bf, acc[mt][ct], 0, 0, 0);
            }
        }
        __syncthreads();
    }

    // ---- epilogue ----
#pragma unroll
    for (int mt = 0; mt < 4; ++mt) {
#pragma unroll
        for (int ct = 0; ct < 2; ++ct) {
            const long row0 = B0 + wm * 64 + mt * 16 + quad * 4;
            const int col = wn * 32 + ct * 16 + m16;
#pragma unroll
            for (int rg = 0; rg < 4; ++rg) {
                const long rr = row0 + rg;
                if (rr < N_NODES) out[rr * CH + col] = acc[mt][ct][rg] + bcol[ct];
            }
        }
    }
}

// ======================= fallback tiers (round-1 code) =======================

__global__ void count_rd_kernel(const int* __restrict__ ei, const int* __restrict__ et,
                                int* __restrict__ cnt) {
    int e = blockIdx.x * 256 + threadIdx.x;
    if (e < N_EDGES) {
        int dst = ei[N_EDGES + e];
        int r = et[e];
        atomicAdd(&cnt[r * N_NODES + dst], 1);
    }
}

__global__ void scatter_kernel(const int* __restrict__ ei, const int* __restrict__ et,
                               const float* __restrict__ x, float* __restrict__ sums,
                               int rel) {
    int gid = (blockIdx.x * 256 + threadIdx.x) >> 5;
    int lane = threadIdx.x & 31;
    int ngroups = gridDim.x * 8;
    for (int e = gid; e < N_EDGES; e += ngroups) {
        if (et[e] != rel) continue;
        int src = ei[e];
        int dst = ei[N_EDGES + e];
        float4 v = ((const float4*)(x + (size_t)src * CH))[lane];
        float* s = sums + (size_t)dst * CH + (size_t)lane * 4;
        atomicAdd(s + 0, v.x);
        atomicAdd(s + 1, v.y);
        atomicAdd(s + 2, v.z);
        atomicAdd(s + 3, v.w);
    }
}

__global__ __launch_bounds__(256, 2)
void gemm_kernel(const float* __restrict__ A, const float* __restrict__ B,
                 const float* __restrict__ bias, const int* __restrict__ cnt,
                 float* __restrict__ out, int accumulate) {
    const int wave = threadIdx.x >> 6;
    const int lane = threadIdx.x & 63;
    const int m16 = lane & 15;
    const int quad = lane >> 4;

    frag_ab bfrag[4][8];
#pragma unroll
    for (int ks = 0; ks < 4; ++ks) {
        const int kb = ks * 32 + quad * 8;
#pragma unroll
        for (int ct = 0; ct < 8; ++ct) {
            const int col = ct * 16 + m16;
            frag_ab f;
#pragma unroll
            for (int j = 0; j < 8; ++j)
                f[j] = f2bs(B[(size_t)(kb + j) * CH + col]);
            bfrag[ks][ct] = f;
        }
    }

    const int nstrips = (N_NODES + 63) / 64;
    for (int strip = blockIdx.x; strip < nstrips; strip += gridDim.x) {
        const int row = strip * 64 + wave * 16 + m16;
        const bool valid = row < N_NODES;
        float scale = 1.0f;
        if (cnt != nullptr && valid) {
            int c = cnt[row];
            if (c > 1) scale = 1.0f / (float)c;
        }
        const float4* arow = (const float4*)(A + (size_t)(valid ? row : 0) * CH);
        frag_cd acc[8];
#pragma unroll
        for (int ct = 0; ct < 8; ++ct) acc[ct] = (frag_cd){0.f, 0.f, 0.f, 0.f};
#pragma unroll
        for (int ks = 0; ks < 4; ++ks) {
            float4 a0 = arow[ks * 8 + quad * 2];
            float4 a1 = arow[ks * 8 + quad * 2 + 1];
            frag_ab af;
            af[0] = f2bs(a0.x * scale); af[1] = f2bs(a0.y * scale);
            af[2] = f2bs(a0.z * scale); af[3] = f2bs(a0.w * scale);
            af[4] = f2bs(a1.x * scale); af[5] = f2bs(a1.y * scale);
            af[6] = f2bs(a1.z * scale); af[7] = f2bs(a1.w * scale);
#pragma unroll
            for (int ct = 0; ct < 8; ++ct)
                acc[ct] = __builtin_amdgcn_mfma_f32_16x16x32_bf16(af, bfrag[ks][ct], acc[ct], 0, 0, 0);
        }
        const int obase = strip * 64 + wave * 16 + quad * 4;
#pragma unroll
        for (int ct = 0; ct < 8; ++ct) {
            const int col = ct * 16 + m16;
#pragma unroll
            for (int rg = 0; rg < 4; ++rg) {
                const int r = obase + rg;
                if (r < N_NODES) {
                    const size_t idx = (size_t)r * CH + col;
                    if (accumulate) out[idx] += acc[ct][rg];
                    else out[idx] = acc[ct][rg] + bias[col];
                }
            }
        }
    }
}

__global__ void edge_transform_kernel(const int* __restrict__ ei, const int* __restrict__ et,
                                      const float* __restrict__ x, const float* __restrict__ W,
                                      const int* __restrict__ cnt, float* __restrict__ out) {
    __shared__ float xs[CH];
    const int tid = threadIdx.x;
    for (int e = blockIdx.x; e < N_EDGES; e += gridDim.x) {
        const int src = ei[e];
        const int dst = ei[N_EDGES + e];
        const int r = et[e];
        __syncthreads();
        xs[tid] = x[(size_t)src * CH + tid];
        __syncthreads();
        const int c = cnt[r * N_NODES + dst];
        const float scale = (c > 1) ? (1.0f / (float)c) : 1.0f;
        const float* Wr = W + (size_t)r * CH * CH;
        float acc = 0.f;
#pragma unroll 8
        for (int k = 0; k < CH; ++k) acc += xs[k] * Wr[(size_t)k * CH + tid];
        atomicAdd(&out[(size_t)dst * CH + tid], acc * scale);
    }
}

// ======================= launch =======================

static inline size_t al512(size_t x) { return (x + 511) & ~(size_t)511; }

extern "C" void kernel_launch(void* const* d_in, const int* in_sizes, int n_in,
                              void* d_out, int out_size, void* d_ws, size_t ws_size,
                              hipStream_t stream) {
    const float* x    = (const float*)d_in[0];
    const int*   ei   = (const int*)d_in[1];   // [2, E]: row0=src, row1=dst
    const int*   et   = (const int*)d_in[2];   // [E]
    const float* W    = (const float*)d_in[3]; // [R,128,128]
    const float* root = (const float*)d_in[4]; // [128,128]
    const float* bias = (const float*)d_in[5]; // [128]
    float* out = (float*)d_out;

    // ---- tier-1 workspace layout (compact per-chunk CSR, 2-kernel pipeline) ----
    size_t o = 0;
    const size_t o_ents = o; o += al512((size_t)NCHUNK * CHUNK_E * 4);        // 6.4 MB
    const size_t o_offs = o; o += al512((size_t)NCHUNK * OFFS_STRIDE * 4);    // 4.9 MB
    const size_t o_bsw  = o; o += al512((size_t)9 * 2048 * 16);
    const size_t o_xb   = o; o += al512((size_t)N_PAD * CH * 2);              // 25.6 MB
    const size_t need_t1 = o;

    const size_t cnt_bytes = (size_t)N_REL * N_NODES * sizeof(int);
    const size_t cnt_rsv   = al512(cnt_bytes);
    const size_t sums51    = (size_t)N_NODES * CH * sizeof(float);

    char* ws = (char*)d_ws;
    if (ws_size >= need_t1) {
        uint32_t* ents = (uint32_t*)(ws + o_ents);
        int*      offs = (int*)(ws + o_offs);
        short*    Bsw  = (short*)(ws + o_bsw);
        short*    xb   = (short*)(ws + o_xb);

        prep_kernel<<<NCHUNK, 256, 0, stream>>>(ei, et, ents, offs, x, xb, root, W, Bsw);
        rgcn_fused<<<NBKT, 512, 0, stream>>>(ents, offs, xb, Bsw, bias, out);
    } else if (ws_size >= cnt_rsv + sums51) {
        int*   cnt  = (int*)d_ws;
        float* sums = (float*)((char*)d_ws + cnt_rsv);
        hipMemsetAsync(cnt, 0, cnt_bytes, stream);
        count_rd_kernel<<<(N_EDGES + 255) / 256, 256, 0, stream>>>(ei, et, cnt);
        gemm_kernel<<<512, 256, 0, stream>>>(x, root, bias, nullptr, out, 0);
        for (int r = 0; r < N_REL; ++r) {
            hipMemsetAsync(sums, 0, sums51, stream);
            scatter_kernel<<<6400, 256, 0, stream>>>(ei, et, x, sums, r);
            gemm_kernel<<<512, 256, 0, stream>>>(sums, W + (size_t)r * CH * CH,
                                                 nullptr, cnt + (size_t)r * N_NODES, out, 1);
        }
    } else {
        int* cnt = (int*)d_ws;
        hipMemsetAsync(cnt, 0, cnt_bytes, stream);
        count_rd_kernel<<<(N_EDGES + 255) / 256, 256, 0, stream>>>(ei, et, cnt);
        gemm_kernel<<<512, 256, 0, stream>>>(x, root, bias, nullptr, out, 0);
        edge_transform_kernel<<<65536, CH, 0, stream>>>(ei, et, x, W, cnt, out);
    }
}